// Round 14
// baseline (14810.179 us; speedup 1.0000x reference)
//
#include <hip/hip_runtime.h>
#include <hip/hip_bf16.h>
#include <cstdint>

#define HIDDEN 1024
#define INPUT  256
#define BATCH  64
#define TSTEPS 512
#define NGCOL  4096      // 4*HIDDEN
#define KTOT   1280      // HIDDEN + INPUT
#define HBUFN  65536     // BATCH*HIDDEN u32 per parity buffer

typedef __attribute__((ext_vector_type(8))) short bf16x8;
typedef __attribute__((ext_vector_type(4))) float f32x4;
typedef unsigned long long u64;
typedef unsigned int u32;

__device__ inline short f2bs(float f) {
    union { __hip_bfloat16 h; short s; } u;
    u.h = __float2bfloat16(f);
    return u.s;
}
__device__ inline unsigned short f2bu(float f) {
    union { __hip_bfloat16 h; unsigned short s; } u;
    u.h = __float2bfloat16(f);
    return u.s;
}

// ---------------------------------------------------------------------------
// P1: build unified transposed bf16 weights Wt[4096 cols][1280 k]
__global__ __launch_bounds__(256) void build_wt(
    const float* __restrict__ Whh, const float* __restrict__ Wih,
    __hip_bfloat16* __restrict__ Wt)
{
    int t = blockIdx.x * 256 + threadIdx.x;   // 0 .. 4096*80-1
    int col = t & 4095;
    int k0  = (t >> 12) * 16;                 // 0..1264
    __hip_bfloat16 tmp[16];
    if (k0 < HIDDEN) {
        #pragma unroll
        for (int i = 0; i < 16; ++i)
            tmp[i] = __float2bfloat16(Whh[(size_t)(k0 + i) * NGCOL + col]);
    } else {
        #pragma unroll
        for (int i = 0; i < 16; ++i)
            tmp[i] = __float2bfloat16(Wih[(size_t)(k0 - HIDDEN + i) * NGCOL + col]);
    }
    #pragma unroll
    for (int i = 0; i < 16; ++i)
        Wt[(size_t)col * KTOT + k0 + i] = tmp[i];
}

// ---------------------------------------------------------------------------
// P2: bias = b_ih + b_hh ; zero all three variants' epoch-coded h buffers
__global__ __launch_bounds__(256) void init_state(
    const float* __restrict__ bih, const float* __restrict__ bhh,
    float* __restrict__ bias, u32* __restrict__ hbuf_all)
{
    int i = blockIdx.x * 256 + threadIdx.x;   // 393216 threads
    if (i < NGCOL) bias[i] = bih[i] + bhh[i];
    hbuf_all[i] = 0u;                          // 3 variants x 2 parities
}

// ---------------------------------------------------------------------------
// Persistent LSTM, ablation-instrumented. Geometry: 512 wgs x 256 thr
// (2 independent wgs/CU -> phase decorrelation), tile = 8 batch rows x
// 16 h-cols. wg i: xsl=i&7 (XCD slot), cg=xsl*8+((i>>3)&7), bg=i>>6.
// Co-resident pair (i, i+256): same cg (shared 160KB W slice), different bg.
// MODE 0: full in-band epoch protocol (burst + verify + parallel re-sweep)
// MODE 1: no-wait  (single burst, no verify loop)   -> wait cost = V0-V1
// MODE 2: cached   (plain loads, no sc1, no verify) -> sc1 cost  = V1-V2
template<int MODE>
__global__ __launch_bounds__(256, 2) void lstm_persist(
    const __hip_bfloat16* __restrict__ Wt,
    const float* __restrict__ x,
    u32* __restrict__ hbuf,              // [2][64][1024] epoch-coded
    float* __restrict__ hf,
    const float* __restrict__ bias)
{
    __shared__ float pbuf[4][4][8][17];  // [wave][gate][row][col+pad] 8.7 KB

    const int tid  = threadIdx.x;
    const int i    = blockIdx.x;          // 0..511
    const int xsl  = i & 7;
    const int j    = i >> 3;              // 0..63
    const int cg   = xsl * 8 + (j & 7);   // 0..63
    const int bg   = j >> 3;              // 0..7
    const int wave = tid >> 6;            // 0..3
    const int lane = tid & 63;
    const int l15  = lane & 15;
    const int l4   = lane >> 4;
    const int b0   = bg * 8;
    const int n0   = cg * 16;

    // B-operand base pointers, one per gate (L2-resident slice)
    const __hip_bfloat16* wgp[4];
    #pragma unroll
    for (int g = 0; g < 4; ++g)
        wgp[g] = Wt + (size_t)(g * 1024 + n0 + l15) * KTOT;

    // reducer state (tid < 128): row = tid>>4 (0..7), hcol = tid&15
    const int rrow = tid >> 4;
    const int rhc  = tid & 15;
    float creg = 0.f;
    float bb[4] = {0.f, 0.f, 0.f, 0.f};
    if (tid < 128) {
        #pragma unroll
        for (int g = 0; g < 4; ++g) bb[g] = bias[g * 1024 + n0 + rhc];
    }

    const bool act  = (l15 < 8);          // MFMA A rows 8..15 zero-padded
    const int  hrow = b0 + l15;
    const float* xrow = x + (size_t)(act ? hrow : 0) * TSTEPS * INPUT;

    for (int t = 0; t < TSTEPS; ++t) {
        const u32* hb = hbuf + (t & 1) * HBUFN;        // holds epoch t
        u32*       ho = hbuf + ((t + 1) & 1) * HBUFN;  // receives epoch t+1

        f32x4 acc[4];
        #pragma unroll
        for (int g = 0; g < 4; ++g) acc[g] = (f32x4){0.f, 0.f, 0.f, 0.f};

        // ---- x-part MFMAs first (chunks wave+32, wave+36; independent of h)
        #pragma unroll
        for (int k = 8; k < 10; ++k) {
            const int kc = wave + 4 * k;               // 32..39
            bf16x8 af = {0, 0, 0, 0, 0, 0, 0, 0};
            if (act) {
                const float* xf = xrow + (size_t)t * INPUT + (kc * 32 + l4 * 8 - 1024);
                float4 pa = *(const float4*)(xf);
                float4 pb = *(const float4*)(xf + 4);
                af[0] = f2bs(pa.x); af[1] = f2bs(pa.y); af[2] = f2bs(pa.z); af[3] = f2bs(pa.w);
                af[4] = f2bs(pb.x); af[5] = f2bs(pb.y); af[6] = f2bs(pb.z); af[7] = f2bs(pb.w);
            }
            #pragma unroll
            for (int g = 0; g < 4; ++g)
                acc[g] = __builtin_amdgcn_mfma_f32_16x16x32_bf16(
                    af, *(const bf16x8*)(wgp[g] + kc * 32 + l4 * 8), acc[g], 0, 0, 0);
        }

        // ---- burst-load h slice: 8 chunks x 4 u64 per active lane
        const u64 want  = ((u64)(u32)t << 16) | ((u64)(u32)t << 48);
        const u64 emask = 0xFFFF0000FFFF0000ull;
        u64 hq[8][4];
        u64 bad = 0;
        if (act) {
            #pragma unroll
            for (int k = 0; k < 8; ++k) {
                const u64* hp = (const u64*)(hb + hrow * HIDDEN + (wave + 4 * k) * 32 + l4 * 8);
                #pragma unroll
                for (int q = 0; q < 4; ++q) {
                    if (MODE == 2) hq[k][q] = hp[q];
                    else hq[k][q] = __hip_atomic_load(hp + q, __ATOMIC_RELAXED,
                                                      __HIP_MEMORY_SCOPE_AGENT);
                    bad |= (hq[k][q] ^ want) & emask;
                }
            }
        }
        if (MODE == 0) {
            while (!__all(bad == 0)) {      // parallel re-sweep (true gate)
                __builtin_amdgcn_s_sleep(1);
                bad = 0;
                if (act) {
                    #pragma unroll
                    for (int k = 0; k < 8; ++k) {
                        const u64* hp = (const u64*)(hb + hrow * HIDDEN + (wave + 4 * k) * 32 + l4 * 8);
                        #pragma unroll
                        for (int q = 0; q < 4; ++q) {
                            hq[k][q] = __hip_atomic_load(hp + q, __ATOMIC_RELAXED,
                                                         __HIP_MEMORY_SCOPE_AGENT);
                            bad |= (hq[k][q] ^ want) & emask;
                        }
                    }
                }
            }
        }

        // ---- repack + h-part MFMAs
        #pragma unroll
        for (int k = 0; k < 8; ++k) {
            bf16x8 af = {0, 0, 0, 0, 0, 0, 0, 0};
            if (act) {
                union { u32 p[4]; bf16x8 v; } u;
                #pragma unroll
                for (int q = 0; q < 4; ++q) {
                    const u64 d = hq[k][q];
                    u.p[q] = (u32)(d & 0xFFFFu) | ((u32)(d >> 32) << 16);
                }
                af = u.v;
            }
            const int kc = wave + 4 * k;
            #pragma unroll
            for (int g = 0; g < 4; ++g)
                acc[g] = __builtin_amdgcn_mfma_f32_16x16x32_bf16(
                    af, *(const bf16x8*)(wgp[g] + kc * 32 + l4 * 8), acc[g], 0, 0, 0);
        }

        // D layout: row = l4*4 + r (valid rows 0..7 -> l4 < 2), col = l15
        if (l4 < 2) {
            #pragma unroll
            for (int r = 0; r < 4; ++r) {
                const int row = l4 * 4 + r;
                #pragma unroll
                for (int g = 0; g < 4; ++g)
                    pbuf[wave][g][row][l15] = acc[g][r];
            }
        }
        __syncthreads();

        if (tid < 128) {
            float gv[4];
            #pragma unroll
            for (int g = 0; g < 4; ++g) {
                float s = bb[g];
                #pragma unroll
                for (int w4 = 0; w4 < 4; ++w4)
                    s += pbuf[w4][g][rrow][rhc];
                gv[g] = s;
            }
            const float i_ = 1.f / (1.f + __expf(-gv[0]));
            const float f_ = 1.f / (1.f + __expf(-gv[1]));
            const float g_ = tanhf(gv[2]);
            const float o_ = 1.f / (1.f + __expf(-gv[3]));
            creg = f_ * creg + i_ * g_;
            const float h = o_ * tanhf(creg);
            if (t == TSTEPS - 1) {
                hf[(b0 + rrow) * HIDDEN + n0 + rhc] = h;
            } else {
                const u32 val = ((u32)(t + 1) << 16) | (u32)f2bu(h);
                __hip_atomic_store(ho + (b0 + rrow) * HIDDEN + n0 + rhc, val,
                                   __ATOMIC_RELAXED, __HIP_MEMORY_SCOPE_AGENT);
            }
        }
        if (t == TSTEPS - 1) break;
        __syncthreads();   // pbuf WAR for next step
    }
}

// ---------------------------------------------------------------------------
// Epilogue: out[64][256] = h_last(fp32) @ W_out + b_out
__global__ __launch_bounds__(256) void out_proj(
    const float* __restrict__ hf, const float* __restrict__ Wout,
    const float* __restrict__ bout, float* __restrict__ out)
{
    const int b  = blockIdx.x;    // 64
    const int oc = threadIdx.x;   // 256
    const float* hb = hf + (size_t)b * HIDDEN;
    float a0 = 0.f, a1 = 0.f, a2 = 0.f, a3 = 0.f;
    for (int k = 0; k < HIDDEN; k += 4) {
        a0 += hb[k + 0] * Wout[(size_t)(k + 0) * 256 + oc];
        a1 += hb[k + 1] * Wout[(size_t)(k + 1) * 256 + oc];
        a2 += hb[k + 2] * Wout[(size_t)(k + 2) * 256 + oc];
        a3 += hb[k + 3] * Wout[(size_t)(k + 3) * 256 + oc];
    }
    out[b * 256 + oc] = (a0 + a1) + (a2 + a3) + bout[oc];
}

// ---------------------------------------------------------------------------
extern "C" void kernel_launch(void* const* d_in, const int* in_sizes, int n_in,
                              void* d_out, int out_size, void* d_ws, size_t ws_size,
                              hipStream_t stream)
{
    const float* x    = (const float*)d_in[0];
    const float* Wih  = (const float*)d_in[1];
    const float* Whh  = (const float*)d_in[2];
    const float* bih  = (const float*)d_in[3];
    const float* bhh  = (const float*)d_in[4];
    const float* Wout = (const float*)d_in[5];
    const float* bout = (const float*)d_in[6];
    float* out = (float*)d_out;

    char* ws = (char*)d_ws;
    size_t off = 0;
    auto alloc = [&](size_t bytes) -> void* {
        void* p = ws + off;
        off = (off + bytes + 255) & ~(size_t)255;
        return p;
    };
    __hip_bfloat16* Wt = (__hip_bfloat16*)alloc((size_t)NGCOL * KTOT * 2); // 10 MB
    u32*   hbufA = (u32*)alloc((size_t)2 * HBUFN * 4);                     // V0
    u32*   hbufB = (u32*)alloc((size_t)2 * HBUFN * 4);                     // V1
    u32*   hbufC = (u32*)alloc((size_t)2 * HBUFN * 4);                     // V2
    float* bias  = (float*)alloc((size_t)NGCOL * 4);
    float* hf    = (float*)alloc((size_t)BATCH * HIDDEN * 4);
    float* hfs1  = (float*)alloc((size_t)BATCH * HIDDEN * 4);
    float* hfs2  = (float*)alloc((size_t)BATCH * HIDDEN * 4);

    build_wt<<<1280, 256, 0, stream>>>(Whh, Wih, Wt);
    init_state<<<1536, 256, 0, stream>>>(bih, bhh, bias, hbufA);  // zeroes A,B,C (contiguous)

    lstm_persist<0><<<512, 256, 0, stream>>>(Wt, x, hbufA, hf,   bias);
    lstm_persist<1><<<512, 256, 0, stream>>>(Wt, x, hbufB, hfs1, bias);
    lstm_persist<2><<<512, 256, 0, stream>>>(Wt, x, hbufC, hfs2, bias);

    out_proj<<<64, 256, 0, stream>>>(hf, Wout, bout, out);
}

// Round 16
// 2883.403 us; speedup vs baseline: 5.1364x; 5.1364x over previous
//
#include <hip/hip_runtime.h>
#include <hip/hip_bf16.h>
#include <cstdint>

#define HIDDEN 1024
#define INPUT  256
#define BATCH  64
#define TSTEPS 512
#define NGCOL  4096      // 4*HIDDEN
#define KTOT   1280      // HIDDEN + INPUT
#define HBUFN  65536     // BATCH*HIDDEN u32 per parity buffer
#define FSTRIDE 16       // flag padding: 16 u32 = 64 B per wg

typedef __attribute__((ext_vector_type(8))) short bf16x8;
typedef __attribute__((ext_vector_type(4))) float f32x4;
typedef unsigned long long u64;
typedef unsigned int u32;

__device__ inline short f2bs(float f) {
    union { __hip_bfloat16 h; short s; } u;
    u.h = __float2bfloat16(f);
    return u.s;
}
__device__ inline unsigned short f2bu(float f) {
    union { __hip_bfloat16 h; unsigned short s; } u;
    u.h = __float2bfloat16(f);
    return u.s;
}

// ---------------------------------------------------------------------------
// P1: build unified transposed bf16 weights Wt[4096 cols][1280 k]
__global__ __launch_bounds__(256) void build_wt(
    const float* __restrict__ Whh, const float* __restrict__ Wih,
    __hip_bfloat16* __restrict__ Wt)
{
    int t = blockIdx.x * 256 + threadIdx.x;   // 0 .. 4096*80-1
    int col = t & 4095;
    int k0  = (t >> 12) * 16;                 // 0..1264
    __hip_bfloat16 tmp[16];
    if (k0 < HIDDEN) {
        #pragma unroll
        for (int i = 0; i < 16; ++i)
            tmp[i] = __float2bfloat16(Whh[(size_t)(k0 + i) * NGCOL + col]);
    } else {
        #pragma unroll
        for (int i = 0; i < 16; ++i)
            tmp[i] = __float2bfloat16(Wih[(size_t)(k0 - HIDDEN + i) * NGCOL + col]);
    }
    #pragma unroll
    for (int i = 0; i < 16; ++i)
        Wt[(size_t)col * KTOT + k0 + i] = tmp[i];
}

// ---------------------------------------------------------------------------
// P2: bias = b_ih + b_hh ; zero epoch-coded h buffers and per-wg flags
__global__ __launch_bounds__(256) void init_state(
    const float* __restrict__ bih, const float* __restrict__ bhh,
    float* __restrict__ bias, u32* __restrict__ hbuf, u32* __restrict__ cnt)
{
    int i = blockIdx.x * 256 + threadIdx.x;   // 131072 threads
    if (i < NGCOL) bias[i] = bih[i] + bhh[i];
    hbuf[i] = 0u;                              // both parity buffers
    if (i < 256 * FSTRIDE) cnt[i] = 0u;
}

// ---------------------------------------------------------------------------
// Persistent LSTM = r8 protocol (verbatim) + loop-invariant W split:
//   gates 0,1: LDS-resident (80 KB, filled ONCE; own-slot -> conflict-free)
//   gates 2,3: issued from L2 ABOVE the flag poll each step (latency hides
//              under the wait; asm pin forces issue before the poll)
// Exchange (r8, proven): reducers store epoch-coded u32 directly;
// __syncthreads (compiler drains vmcnt per-thread); tid0 stores per-wg flag;
// consumers: wave-parallel flag poll -> burst sweep + epoch verify.
// 256 wgs: bg = wg>>6 (16 batch rows), cg = wg&63 (16 h-cols -> 64 gate cols).
__global__ __launch_bounds__(512, 2) void lstm_persist(
    const __hip_bfloat16* __restrict__ Wt,
    const float* __restrict__ x,
    u32* __restrict__ hbuf,              // [2][64][1024] epoch-coded
    float* __restrict__ hf,
    const float* __restrict__ bias,
    u32* __restrict__ cnt)               // [256][FSTRIDE] flags
{
    __shared__ float pbuf[8][1025];                                   // 32.8 KB
    __shared__ __attribute__((aligned(16))) short wlds[2][5][512][8]; // 80 KB

    const int tid  = threadIdx.x;
    const int wg   = blockIdx.x;
    const int bg   = wg >> 6;         // 0..3
    const int cg   = wg & 63;         // 0..63
    const int wave = tid >> 6;
    const int lane = tid & 63;
    const int l15  = lane & 15;
    const int l4   = lane >> 4;
    const int b0   = bg * 16;
    const int n0   = cg * 16;

    const __hip_bfloat16* wrow = Wt + (size_t)(n0 + l15) * KTOT;

    // ---- one-time: gates 0,1 W fragments into LDS (own slot per thread)
    #pragma unroll
    for (int c5 = 0; c5 < 5; ++c5) {
        const int kk = (wave + c5 * 8) * 32 + l4 * 8;
        *(bf16x8*)&wlds[0][c5][tid][0] = *(const bf16x8*)(wrow + kk);
        *(bf16x8*)&wlds[1][c5][tid][0] =
            *(const bf16x8*)(wrow + (size_t)1024 * KTOT + kk);
    }

    // ---- persistent per-thread state for reducer threads (tid<256)
    const int br = tid >> 4;          // batch row within group
    const int hc = tid & 15;          // h-col within group
    float creg = 0.f;
    float bi = 0.f, bfr = 0.f, bgg = 0.f, bo = 0.f;
    if (tid < 256) {
        bi  = bias[0 * 1024 + n0 + hc];
        bfr = bias[1 * 1024 + n0 + hc];
        bgg = bias[2 * 1024 + n0 + hc];
        bo  = bias[3 * 1024 + n0 + hc];
    }

    const int hoff = (b0 + l15) * HIDDEN + wave * 32 + l4 * 8;   // u32 units
    const float* xrow = x + ((size_t)(b0 + l15) * TSTEPS) * INPUT + wave * 32 + l4 * 8;

    // this wave's 8 producer wgs: cg = 2*wave + (j&1) + 16*(j>>1), j = lane&7
    const int pj = 2 * wave + (lane & 1) + 16 * ((lane >> 1) & 3);
    const u32* myflag = cnt + (size_t)(bg * 64 + pj) * FSTRIDE;

    for (int t = 0; t < TSTEPS; ++t) {
        const u32* hb = hbuf + (t & 1) * HBUFN;        // holds epoch t
        u32*       ho = hbuf + ((t + 1) & 1) * HBUFN;  // receives epoch t+1

        // ---- pre-poll: issue gates 2,3 W loads (h-independent); pin forces
        //      materialization before the opaque poll -> latency hides there.
        bf16x8 w2[5], w3[5];
        #pragma unroll
        for (int c5 = 0; c5 < 5; ++c5) {
            const int kk = (wave + c5 * 8) * 32 + l4 * 8;
            w2[c5] = *(const bf16x8*)(wrow + (size_t)2048 * KTOT + kk);
            w3[c5] = *(const bf16x8*)(wrow + (size_t)3072 * KTOT + kk);
        }
        #pragma unroll
        for (int c5 = 0; c5 < 5; ++c5) {
            asm volatile("" : "+v"(w2[c5]));
            asm volatile("" : "+v"(w3[c5]));
        }

        // ---- x fragment + x-part MFMAs (independent of h)
        bf16x8 afx;
        {
            const float* xf = xrow + (size_t)t * INPUT;
            float4 pa = *(const float4*)(xf);
            float4 pb = *(const float4*)(xf + 4);
            afx[0] = f2bs(pa.x); afx[1] = f2bs(pa.y); afx[2] = f2bs(pa.z); afx[3] = f2bs(pa.w);
            afx[4] = f2bs(pb.x); afx[5] = f2bs(pb.y); afx[6] = f2bs(pb.z); afx[7] = f2bs(pb.w);
        }
        f32x4 a0 = {0.f, 0.f, 0.f, 0.f};
        f32x4 a1 = a0, a2 = a0, a3 = a0;
        a0 = __builtin_amdgcn_mfma_f32_16x16x32_bf16(
                 afx, *(const bf16x8*)&wlds[0][4][tid][0], a0, 0, 0, 0);
        a1 = __builtin_amdgcn_mfma_f32_16x16x32_bf16(
                 afx, *(const bf16x8*)&wlds[1][4][tid][0], a1, 0, 0, 0);
        a2 = __builtin_amdgcn_mfma_f32_16x16x32_bf16(afx, w2[4], a2, 0, 0, 0);
        a3 = __builtin_amdgcn_mfma_f32_16x16x32_bf16(afx, w3[4], a3, 0, 0, 0);

        // ---- flag pre-filter: 1 u32 per lane, 8 producers per wave (r8)
        for (;;) {
            u32 f = __hip_atomic_load(myflag, __ATOMIC_RELAXED, __HIP_MEMORY_SCOPE_AGENT);
            if (__all(f >= (u32)t)) break;
            __builtin_amdgcn_s_sleep(1);
        }

        // ---- data read + epoch verify (true gate; rare short retry)
        u64 hq[4][4];
        {
            const u64 want = ((u64)(u32)t << 16) | ((u64)(u32)t << 48);
            const u64 mask = 0xFFFF0000FFFF0000ull;
            for (;;) {
                u64 bad = 0;
                #pragma unroll
                for (int c5 = 0; c5 < 4; ++c5) {
                    const u64* hp = (const u64*)(hb + hoff + c5 * 256);
                    #pragma unroll
                    for (int q = 0; q < 4; ++q) {
                        hq[c5][q] = __hip_atomic_load(hp + q, __ATOMIC_RELAXED,
                                                      __HIP_MEMORY_SCOPE_AGENT);
                        bad |= (hq[c5][q] ^ want) & mask;
                    }
                }
                if (__all(bad == 0)) break;
                __builtin_amdgcn_s_sleep(1);
            }
        }
        // ---- repack: u64 (2 epoch-coded u32) -> packed bf16 pair
        bf16x8 afh[4];
        #pragma unroll
        for (int c5 = 0; c5 < 4; ++c5) {
            union { u32 p[4]; bf16x8 v; } u;
            #pragma unroll
            for (int q = 0; q < 4; ++q) {
                const u64 d = hq[c5][q];
                u.p[q] = (u32)(d & 0xFFFFu) | ((u32)(d >> 32) << 16);
            }
            afh[c5] = u.v;
        }

        // ---- h MFMAs: gates 0,1 B from LDS; gates 2,3 from prefetched regs
        #pragma unroll
        for (int c5 = 0; c5 < 4; ++c5) {
            a0 = __builtin_amdgcn_mfma_f32_16x16x32_bf16(
                     afh[c5], *(const bf16x8*)&wlds[0][c5][tid][0], a0, 0, 0, 0);
            a1 = __builtin_amdgcn_mfma_f32_16x16x32_bf16(
                     afh[c5], *(const bf16x8*)&wlds[1][c5][tid][0], a1, 0, 0, 0);
            a2 = __builtin_amdgcn_mfma_f32_16x16x32_bf16(afh[c5], w2[c5], a2, 0, 0, 0);
            a3 = __builtin_amdgcn_mfma_f32_16x16x32_bf16(afh[c5], w3[c5], a3, 0, 0, 0);
        }

        // D layout: row (batch) = l4*4 + r, col (h-col) = l15
        float* pw = &pbuf[wave][0];
        #pragma unroll
        for (int r = 0; r < 4; ++r) {
            const int row = l4 * 4 + r;
            pw[(0 * 16 + row) * 16 + l15] = a0[r];
            pw[(1 * 16 + row) * 16 + l15] = a1[r];
            pw[(2 * 16 + row) * 16 + l15] = a2[r];
            pw[(3 * 16 + row) * 16 + l15] = a3[r];
        }
        __syncthreads();

        if (tid < 256) {
            float gi = bi, gf = bfr, gg = bgg, go = bo;
            #pragma unroll
            for (int w8 = 0; w8 < 8; ++w8) {
                const float* p = &pbuf[w8][0];
                gi += p[(0 * 16 + br) * 16 + hc];
                gf += p[(1 * 16 + br) * 16 + hc];
                gg += p[(2 * 16 + br) * 16 + hc];
                go += p[(3 * 16 + br) * 16 + hc];
            }
            const float i_ = 1.f / (1.f + __expf(-gi));
            const float f_ = 1.f / (1.f + __expf(-gf));
            const float g_ = tanhf(gg);
            const float o_ = 1.f / (1.f + __expf(-go));
            creg = f_ * creg + i_ * g_;
            const float h = o_ * tanhf(creg);
            if (t == TSTEPS - 1) {
                hf[(b0 + br) * HIDDEN + n0 + hc] = h;
            } else {
                // direct epoch-coded store (r8 verbatim; every element covered)
                const u32 val = ((u32)(t + 1) << 16) | (u32)f2bu(h);
                __hip_atomic_store(ho + (b0 + br) * HIDDEN + n0 + hc, val,
                                   __ATOMIC_RELAXED, __HIP_MEMORY_SCOPE_AGENT);
            }
        }
        if (t == TSTEPS - 1) break;
        __syncthreads();   // per-thread vmcnt drain + barrier: data stores done

        if (tid == 0)      // release flag (data already at coherence point)
            __hip_atomic_store(cnt + (size_t)wg * FSTRIDE, (u32)(t + 1),
                               __ATOMIC_RELAXED, __HIP_MEMORY_SCOPE_AGENT);
    }
}

// ---------------------------------------------------------------------------
// Epilogue: out[64][256] = h_last(fp32) @ W_out + b_out
__global__ __launch_bounds__(256) void out_proj(
    const float* __restrict__ hf, const float* __restrict__ Wout,
    const float* __restrict__ bout, float* __restrict__ out)
{
    const int b  = blockIdx.x;    // 64
    const int oc = threadIdx.x;   // 256
    const float* hb = hf + (size_t)b * HIDDEN;
    float a0 = 0.f, a1 = 0.f, a2 = 0.f, a3 = 0.f;
    for (int k = 0; k < HIDDEN; k += 4) {
        a0 += hb[k + 0] * Wout[(size_t)(k + 0) * 256 + oc];
        a1 += hb[k + 1] * Wout[(size_t)(k + 1) * 256 + oc];
        a2 += hb[k + 2] * Wout[(size_t)(k + 2) * 256 + oc];
        a3 += hb[k + 3] * Wout[(size_t)(k + 3) * 256 + oc];
    }
    out[b * 256 + oc] = (a0 + a1) + (a2 + a3) + bout[oc];
}

// ---------------------------------------------------------------------------
extern "C" void kernel_launch(void* const* d_in, const int* in_sizes, int n_in,
                              void* d_out, int out_size, void* d_ws, size_t ws_size,
                              hipStream_t stream)
{
    const float* x    = (const float*)d_in[0];
    const float* Wih  = (const float*)d_in[1];
    const float* Whh  = (const float*)d_in[2];
    const float* bih  = (const float*)d_in[3];
    const float* bhh  = (const float*)d_in[4];
    const float* Wout = (const float*)d_in[5];
    const float* bout = (const float*)d_in[6];
    float* out = (float*)d_out;

    char* ws = (char*)d_ws;
    size_t off = 0;
    auto alloc = [&](size_t bytes) -> void* {
        void* p = ws + off;
        off = (off + bytes + 255) & ~(size_t)255;
        return p;
    };
    __hip_bfloat16* Wt = (__hip_bfloat16*)alloc((size_t)NGCOL * KTOT * 2); // 10 MB
    u32*   hbuf = (u32*)alloc((size_t)2 * HBUFN * 4);                      // 512 KB
    float* bias = (float*)alloc((size_t)NGCOL * 4);
    float* hf   = (float*)alloc((size_t)BATCH * HIDDEN * 4);
    u32*   cnt  = (u32*)alloc((size_t)256 * FSTRIDE * 4);                  // 16 KB

    build_wt<<<1280, 256, 0, stream>>>(Whh, Wih, Wt);
    init_state<<<512, 256, 0, stream>>>(bih, bhh, bias, hbuf, cnt);
    lstm_persist<<<256, 512, 0, stream>>>(Wt, x, hbuf, hf, bias, cnt);
    out_proj<<<64, 256, 0, stream>>>(hf, Wout, bout, out);
}